// Round 1
// baseline (14761.009 us; speedup 1.0000x reference)
//
#include <hip/hip_runtime.h>
#include <cstdint>

// ---------------------------------------------------------------------------
// ConvGRU-Attention autoencoder, fp32 reference-faithful implementation.
// B=64, T=128, F=64 (spatial H=64, W=1 -> conv is 1-D k=3 over F, kw=1 col).
// Strategy:
//   * conv over concat([x,h]) split into x-part (precomputed for all t,
//     parallel) + h-part (sequential, persistent per-batch workgroup).
//   * t processed in 4 chunks of 32 to keep workspace ~320 MB.
//   * attention: query len == 1 -> fold W_k into query and W_v past softmax
//     (exact reassociation; kills the 550 GF K/V GEMMs).
// ---------------------------------------------------------------------------

#define B_  64
#define T_  128
#define TC  32
#define NCH 4

__device__ __forceinline__ float wsum(float v) {
#pragma unroll
  for (int m = 32; m > 0; m >>= 1) v += __shfl_xor(v, m, 64);
  return v;
}
__device__ __forceinline__ float wmaxr(float v) {
#pragma unroll
  for (int m = 32; m > 0; m >>= 1) v = fmaxf(v, __shfl_xor(v, m, 64));
  return v;
}
__device__ __forceinline__ float sigmoidf_(float x) {
  return 1.f / (1.f + __expf(-x));
}
__device__ __forceinline__ float tanhf_(float x) {
  x = fminf(fmaxf(x, -15.f), 15.f);
  float e2 = __expf(2.f * x);
  return (e2 - 1.f) / (e2 + 1.f);
}

// --------------------------------------------------------------------------
// Repack conv weights: src [OC][INTOT][3][3] -> dst [OC][icN][3] taking
// input-channel range [ic0, ic0+icN) and the middle kw column (kw=1).
// --------------------------------------------------------------------------
__global__ __launch_bounds__(256) void pack_kernel(
    const float* __restrict__ src, float* __restrict__ dst,
    int INTOT, int ic0, int icN, int total) {
  int i = blockIdx.x * 256 + threadIdx.x;
  if (i >= total) return;
  int per_oc = icN * 3;
  int oc = i / per_oc;
  int rem = i - oc * per_oc;
  int j = rem / 3, dk = rem - j * 3;
  dst[i] = src[((size_t)(oc * INTOT + ic0 + j) * 3 + dk) * 3 + 1];
}

// --------------------------------------------------------------------------
// x-part of both convs (gates then cand) for one t-chunk.
// out A[b][tl][OG+OCC][64] = bias + sum_{ic,dk} W[oc][ic][dk]*in[ic][f+dk-1]
// One WG per (b, tl). 256 threads: ocg = tid>>3 (0..31), f0 = (tid&7)*8.
// --------------------------------------------------------------------------
template <int INC, int OG, int OCC>
__global__ __launch_bounds__(256) void conv_x_kernel(
    const float* __restrict__ seq, int seqC, size_t sB,
    const float* __restrict__ ctx,  // broadcast [b][INC-seqC][64] or null
    const float* __restrict__ Wgx, const float* __restrict__ Wcx,
    const float* __restrict__ bg, const float* __restrict__ bc,
    float* __restrict__ out) {
  constexpr int OCT = OG + OCC;
  constexpr int NJ = OG / 32;
  constexpr int NJC = OCC / 32;
  const int btl = blockIdx.x;   // b*TC + tl
  const int b = btl >> 5;
  const int tl = btl & 31;
  const int ocg = threadIdx.x >> 3;
  const int f0 = (threadIdx.x & 7) << 3;
  __shared__ float sin_[INC][72];  // halo at [0], data at [1..64]

  for (int idx = threadIdx.x; idx < INC * 72; idx += 256) {
    int ic = idx / 72, ff = idx - ic * 72;
    float v = 0.f;
    if (ff >= 1 && ff <= 64) {
      int fs = ff - 1;
      v = (ic < seqC)
              ? seq[(size_t)b * sB + (size_t)tl * seqC * 64 + ic * 64 + fs]
              : ctx[((size_t)b * (INC - seqC) + (ic - seqC)) * 64 + fs];
    }
    sin_[ic][ff] = v;
  }
  __syncthreads();

  // ---- gates ----
  {
    float acc[NJ][8];
#pragma unroll
    for (int j = 0; j < NJ; ++j) {
      float bb = bg[ocg + 32 * j];
#pragma unroll
      for (int ff = 0; ff < 8; ++ff) acc[j][ff] = bb;
    }
    for (int ic = 0; ic < INC; ++ic) {
      float4 a4 = *(const float4*)&sin_[ic][f0];
      float4 b4 = *(const float4*)&sin_[ic][f0 + 4];
      float2 c2 = *(const float2*)&sin_[ic][f0 + 8];
      float hv[10] = {a4.x, a4.y, a4.z, a4.w, b4.x, b4.y, b4.z, b4.w, c2.x, c2.y};
#pragma unroll
      for (int j = 0; j < NJ; ++j) {
        const int oc = ocg + 32 * j;
        const float* w = Wgx + ((size_t)oc * INC + ic) * 3;
        const float w0 = w[0], w1 = w[1], w2 = w[2];
#pragma unroll
        for (int ff = 0; ff < 8; ++ff)
          acc[j][ff] = fmaf(w0, hv[ff], fmaf(w1, hv[ff + 1], fmaf(w2, hv[ff + 2], acc[j][ff])));
      }
    }
#pragma unroll
    for (int j = 0; j < NJ; ++j) {
      const int oc = ocg + 32 * j;
      float* dst = out + ((size_t)btl * OCT + oc) * 64 + f0;
      *(float4*)dst = make_float4(acc[j][0], acc[j][1], acc[j][2], acc[j][3]);
      *(float4*)(dst + 4) = make_float4(acc[j][4], acc[j][5], acc[j][6], acc[j][7]);
    }
  }
  // ---- cand ----
  {
    float acc[NJC][8];
#pragma unroll
    for (int j = 0; j < NJC; ++j) {
      float bb = bc[ocg + 32 * j];
#pragma unroll
      for (int ff = 0; ff < 8; ++ff) acc[j][ff] = bb;
    }
    for (int ic = 0; ic < INC; ++ic) {
      float4 a4 = *(const float4*)&sin_[ic][f0];
      float4 b4 = *(const float4*)&sin_[ic][f0 + 4];
      float2 c2 = *(const float2*)&sin_[ic][f0 + 8];
      float hv[10] = {a4.x, a4.y, a4.z, a4.w, b4.x, b4.y, b4.z, b4.w, c2.x, c2.y};
#pragma unroll
      for (int j = 0; j < NJC; ++j) {
        const int oc = ocg + 32 * j;
        const float* w = Wcx + ((size_t)oc * INC + ic) * 3;
        const float w0 = w[0], w1 = w[1], w2 = w[2];
#pragma unroll
        for (int ff = 0; ff < 8; ++ff)
          acc[j][ff] = fmaf(w0, hv[ff], fmaf(w1, hv[ff + 1], fmaf(w2, hv[ff + 2], acc[j][ff])));
      }
    }
#pragma unroll
    for (int j = 0; j < NJC; ++j) {
      const int oc = ocg + 32 * j;
      float* dst = out + ((size_t)btl * OCT + OG + oc) * 64 + f0;
      *(float4*)dst = make_float4(acc[j][0], acc[j][1], acc[j][2], acc[j][3]);
      *(float4*)(dst + 4) = make_float4(acc[j][4], acc[j][5], acc[j][6], acc[j][7]);
    }
  }
}

// --------------------------------------------------------------------------
// Sequential GRU recurrence over one t-chunk (32 steps). One WG per batch.
// 512 threads: ocg = tid>>4 (0..31), f0 = (tid&15)*4.
//   g  = A_gates + Wgh (*) h        ; r,u = sigmoid split
//   c  = A_cand  + Wch (*) (r*h)    ; h' = (1-u)h + u tanh(c)
// u stays in registers: gate oc = cand oc + HC maps to the same thread.
// --------------------------------------------------------------------------
template <int HC, int OG>
__global__ __launch_bounds__(512) void gru_rec_kernel(
    const float* __restrict__ A,          // [b][TC][OG+HC][64] chunk-local
    const float* __restrict__ Wgh,        // [OG][HC][3]
    const float* __restrict__ Wch,        // [HC][HC][3]
    const float* __restrict__ hinit,      // [b][HC][64]
    float* __restrict__ Y, size_t yB,     // Y[b*yB + tl*HC*64 + oc*64 + f]
    float* __restrict__ hfinal) {         // [b][HC][64]
  constexpr int OCT = OG + HC;
  constexpr int NJ = OG / 32;
  constexpr int NJC = HC / 32;
  const int b = blockIdx.x;
  const int ocg = threadIdx.x >> 4;
  const int f0 = (threadIdx.x & 15) << 2;
  __shared__ float hs[HC][72];
  __shared__ float rhs[HC][72];

  for (int idx = threadIdx.x; idx < HC * 72; idx += 512) {
    int c = idx / 72, ff = idx - c * 72;
    float v = 0.f;
    if (ff >= 1 && ff <= 64) v = hinit[((size_t)b * HC + c) * 64 + ff - 1];
    hs[c][ff] = v;
    rhs[c][ff] = 0.f;
  }
  __syncthreads();

  for (int tl = 0; tl < TC; ++tl) {
    const float* Abt = A + ((size_t)b * TC + tl) * (OCT * 64);
    float ur[NJC][4];
    // -------- phase A: gates --------
    {
      float acc[NJ][4];
#pragma unroll
      for (int j = 0; j < NJ; ++j) {
        const int oc = ocg + 32 * j;
        float4 v = *(const float4*)(Abt + oc * 64 + f0);
        acc[j][0] = v.x; acc[j][1] = v.y; acc[j][2] = v.z; acc[j][3] = v.w;
      }
#pragma unroll 2
      for (int hc = 0; hc < HC; ++hc) {
        float4 a4 = *(const float4*)&hs[hc][f0];
        float2 b2 = *(const float2*)&hs[hc][f0 + 4];
        float hv[6] = {a4.x, a4.y, a4.z, a4.w, b2.x, b2.y};
#pragma unroll
        for (int j = 0; j < NJ; ++j) {
          const int oc = ocg + 32 * j;
          const float* w = Wgh + ((size_t)oc * HC + hc) * 3;
          const float w0 = w[0], w1 = w[1], w2 = w[2];
#pragma unroll
          for (int ff = 0; ff < 4; ++ff)
            acc[j][ff] = fmaf(w0, hv[ff], fmaf(w1, hv[ff + 1], fmaf(w2, hv[ff + 2], acc[j][ff])));
        }
      }
#pragma unroll
      for (int j = 0; j < NJ; ++j) {
        const int oc = ocg + 32 * j;
#pragma unroll
        for (int ff = 0; ff < 4; ++ff) {
          float s = sigmoidf_(acc[j][ff]);
          if (j < NJC) rhs[oc][f0 + ff + 1] = s * hs[oc][f0 + ff + 1];  // r*h
          else ur[j - NJC][ff] = s;                                     // u
        }
      }
    }
    __syncthreads();
    // -------- phase B: cand + state update --------
    {
      float acc[NJC][4];
#pragma unroll
      for (int j = 0; j < NJC; ++j) {
        const int oc = ocg + 32 * j;
        float4 v = *(const float4*)(Abt + (OG + oc) * 64 + f0);
        acc[j][0] = v.x; acc[j][1] = v.y; acc[j][2] = v.z; acc[j][3] = v.w;
      }
#pragma unroll 2
      for (int hc = 0; hc < HC; ++hc) {
        float4 a4 = *(const float4*)&rhs[hc][f0];
        float2 b2 = *(const float2*)&rhs[hc][f0 + 4];
        float hv[6] = {a4.x, a4.y, a4.z, a4.w, b2.x, b2.y};
#pragma unroll
        for (int j = 0; j < NJC; ++j) {
          const int oc = ocg + 32 * j;
          const float* w = Wch + ((size_t)oc * HC + hc) * 3;
          const float w0 = w[0], w1 = w[1], w2 = w[2];
#pragma unroll
          for (int ff = 0; ff < 4; ++ff)
            acc[j][ff] = fmaf(w0, hv[ff], fmaf(w1, hv[ff + 1], fmaf(w2, hv[ff + 2], acc[j][ff])));
        }
      }
#pragma unroll
      for (int j = 0; j < NJC; ++j) {
        const int oc = ocg + 32 * j;
        float4 yv;
#pragma unroll
        for (int ff = 0; ff < 4; ++ff) {
          float cd = tanhf_(acc[j][ff]);
          float uu = ur[j][ff];
          float hold = hs[oc][f0 + ff + 1];
          float hn = (1.f - uu) * hold + uu * cd;
          hs[oc][f0 + ff + 1] = hn;  // safe: only owner reads/writes this slot
          (&yv.x)[ff] = hn;
        }
        *(float4*)(Y + (size_t)b * yB + (size_t)tl * (HC * 64) + oc * 64 + f0) = yv;
      }
    }
    __syncthreads();
  }
  for (int idx = threadIdx.x; idx < HC * 64; idx += 512) {
    int c = idx >> 6, ff = idx & 63;
    hfinal[((size_t)b * HC + c) * 64 + ff] = hs[c][ff + 1];
  }
}

// --------------------------------------------------------------------------
// Small fp32 GEMM: O[b][e] = sum_k Wop[e][k] * X[b][k] + bias[e]
// M=64 (batch), one WG per 64-wide e-block; optional per-head pointer shifts.
// WT=false: W row-major [e][k] (row stride wrs). WT=true: W is [k][e].
// --------------------------------------------------------------------------
template <bool WT>
__global__ __launch_bounds__(256) void gemm64_kernel(
    const float* __restrict__ W, int wrs,
    const float* __restrict__ X, int xrs,
    float* __restrict__ O, int ors,
    const float* __restrict__ bias, int K,
    int ebh, size_t hsW, size_t hsX, size_t hsO, size_t hsB) {
  int eb = blockIdx.x;
  if (ebh > 0) {
    int h = blockIdx.x / ebh;
    eb = blockIdx.x - h * ebh;
    W += h * hsW; X += h * hsX; O += h * hsO;
    if (bias) bias += h * hsB;
  }
  const int e0 = eb * 64;
  __shared__ float Xs[64][68];  // [k][b]
  __shared__ float Ws[64][68];  // [k][e]
  const int tb4 = (threadIdx.x & 15) << 2;
  const int te4 = (threadIdx.x >> 4) << 2;
  float acc[4][4] = {};
  for (int k0 = 0; k0 < K; k0 += 64) {
    {
      const int row = threadIdx.x >> 2;        // b
      const int kq = (threadIdx.x & 3) << 4;
      const float* src = X + (size_t)row * xrs + k0 + kq;
#pragma unroll
      for (int q = 0; q < 4; ++q) {
        float4 v = *(const float4*)(src + (q << 2));
        Xs[kq + (q << 2) + 0][row] = v.x;
        Xs[kq + (q << 2) + 1][row] = v.y;
        Xs[kq + (q << 2) + 2][row] = v.z;
        Xs[kq + (q << 2) + 3][row] = v.w;
      }
    }
    if (!WT) {
      const int row = threadIdx.x >> 2;        // e
      const int kq = (threadIdx.x & 3) << 4;
      const float* src = W + (size_t)(e0 + row) * wrs + k0 + kq;
#pragma unroll
      for (int q = 0; q < 4; ++q) {
        float4 v = *(const float4*)(src + (q << 2));
        Ws[kq + (q << 2) + 0][row] = v.x;
        Ws[kq + (q << 2) + 1][row] = v.y;
        Ws[kq + (q << 2) + 2][row] = v.z;
        Ws[kq + (q << 2) + 3][row] = v.w;
      }
    } else {
      const int row = threadIdx.x >> 2;        // k
      const int eq = (threadIdx.x & 3) << 4;
      const float* src = W + (size_t)(k0 + row) * wrs + e0 + eq;
#pragma unroll
      for (int q = 0; q < 4; ++q)
        *(float4*)&Ws[row][eq + (q << 2)] = *(const float4*)(src + (q << 2));
    }
    __syncthreads();
#pragma unroll 8
    for (int k = 0; k < 64; ++k) {
      float4 xv = *(const float4*)&Xs[k][tb4];
      float4 wv4 = *(const float4*)&Ws[k][te4];
      const float xb[4] = {xv.x, xv.y, xv.z, xv.w};
      const float we[4] = {wv4.x, wv4.y, wv4.z, wv4.w};
#pragma unroll
      for (int i = 0; i < 4; ++i)
#pragma unroll
        for (int j = 0; j < 4; ++j) acc[i][j] = fmaf(xb[i], we[j], acc[i][j]);
    }
    __syncthreads();
  }
#pragma unroll
  for (int i = 0; i < 4; ++i)
#pragma unroll
    for (int j = 0; j < 4; ++j) {
      float v = acc[i][j];
      if (bias) v += bias[e0 + te4 + j];
      O[(size_t)(tb4 + i) * ors + e0 + te4 + j] = v;
    }
}

// --------------------------------------------------------------------------
// Attention core (query len 1, folded form). One WG (256 thr) per batch b.
// scores[h][t] = (sum_e qk[b,h,e]*mem[b,t,e] + q_h.bk_h) / 32
// attn = softmax_t ; wmem[b][h][e] = sum_t attn[h][t]*mem[b,t,e]
// --------------------------------------------------------------------------
__global__ __launch_bounds__(256) void attn_core_kernel(
    const float* __restrict__ qkh,   // [b][4][4096]
    const float* __restrict__ qbuf,  // [b][4096]
    const float* __restrict__ bqkv,  // b_qkv (bk at +4096)
    const float* __restrict__ mem,   // [b][128][4096]
    float* __restrict__ wmem) {      // [b][4][4096]
  const int b = blockIdx.x;
  const int wave = threadIdx.x >> 6;
  const int lane = threadIdx.x & 63;
  __shared__ float attn_s[4][128];

  const float* bk = bqkv + 4096;
  float qb = 0.f;
  for (int d = lane; d < 1024; d += 64)
    qb = fmaf(qbuf[(size_t)b * 4096 + wave * 1024 + d], bk[wave * 1024 + d], qb);
  qb = wsum(qb);

  const float* qk = qkh + ((size_t)b * 4 + wave) * 4096;
  for (int t = 0; t < 128; ++t) {
    const float* m = mem + ((size_t)b * 128 + t) * 4096;
    float s = 0.f;
    for (int e = lane; e < 4096; e += 64) s = fmaf(qk[e], m[e], s);
    s = wsum(s);
    if (lane == 0) attn_s[wave][t] = (s + qb) * 0.03125f;
  }
  __syncthreads();
  {
    float s0 = attn_s[wave][lane], s1 = attn_s[wave][lane + 64];
    float mx = wmaxr(fmaxf(s0, s1));
    float e0v = __expf(s0 - mx), e1v = __expf(s1 - mx);
    float inv = 1.f / wsum(e0v + e1v);
    attn_s[wave][lane] = e0v * inv;
    attn_s[wave][lane + 64] = e1v * inv;
  }
  __syncthreads();
  for (int e = threadIdx.x; e < 4096; e += 256) {
    float a0 = 0, a1 = 0, a2 = 0, a3 = 0;
    const float* mb = mem + (size_t)b * 128 * 4096 + e;
    for (int t = 0; t < 128; ++t) {
      float m = mb[(size_t)t * 4096];
      a0 = fmaf(attn_s[0][t], m, a0);
      a1 = fmaf(attn_s[1][t], m, a1);
      a2 = fmaf(attn_s[2][t], m, a2);
      a3 = fmaf(attn_s[3][t], m, a3);
    }
    wmem[((size_t)b * 4 + 0) * 4096 + e] = a0;
    wmem[((size_t)b * 4 + 1) * 4096 + e] = a1;
    wmem[((size_t)b * 4 + 2) * 4096 + e] = a2;
    wmem[((size_t)b * 4 + 3) * 4096 + e] = a3;
  }
}

// --------------------------------------------------------------------------
// Final 1x1 conv for one t-chunk: out[b, tOff+tl, f] = b_fin + sum_c w_fin[c]*z1[...]
// --------------------------------------------------------------------------
__global__ __launch_bounds__(256) void final_kernel(
    const float* __restrict__ z1c,  // [b][TC][32][64]
    const float* __restrict__ wfin, const float* __restrict__ bfin,
    float* __restrict__ out, int tOff) {
  const int idx = blockIdx.x * 256 + threadIdx.x;  // < 64*32*64
  const int f = idx & 63;
  const int tl = (idx >> 6) & 31;
  const int b = idx >> 11;
  const float* zp = z1c + ((size_t)b * TC + tl) * 2048 + f;
  float a = bfin[0];
#pragma unroll
  for (int c = 0; c < 32; ++c) a = fmaf(wfin[c], zp[c * 64], a);
  out[(size_t)b * 8192 + (size_t)(tOff + tl) * 64 + f] = a;
}

// ==========================================================================
extern "C" void kernel_launch(void* const* d_in, const int* in_sizes, int n_in,
                              void* d_out, int out_size, void* d_ws, size_t ws_size,
                              hipStream_t stream) {
  (void)in_sizes; (void)n_in; (void)out_size;
  const float* x     = (const float*)d_in[0];
  const float* wg_e0 = (const float*)d_in[1];
  const float* bg_e0 = (const float*)d_in[2];
  const float* wc_e0 = (const float*)d_in[3];
  const float* bc_e0 = (const float*)d_in[4];
  const float* wg_e1 = (const float*)d_in[5];
  const float* bg_e1 = (const float*)d_in[6];
  const float* wc_e1 = (const float*)d_in[7];
  const float* bc_e1 = (const float*)d_in[8];
  const float* wg_d0 = (const float*)d_in[9];
  const float* bg_d0 = (const float*)d_in[10];
  const float* wc_d0 = (const float*)d_in[11];
  const float* bc_d0 = (const float*)d_in[12];
  const float* wg_d1 = (const float*)d_in[13];
  const float* bg_d1 = (const float*)d_in[14];
  const float* wc_d1 = (const float*)d_in[15];
  const float* bc_d1 = (const float*)d_in[16];
  const float* w_qkv = (const float*)d_in[17];
  const float* b_qkv = (const float*)d_in[18];
  const float* w_out = (const float*)d_in[19];
  const float* b_out = (const float*)d_in[20];
  const float* w_fin = (const float*)d_in[21];
  const float* b_fin = (const float*)d_in[22];
  float* out = (float*)d_out;

  float* WS = (float*)d_ws;
  size_t off = 0;
  auto alloc = [&](size_t n) { float* p = WS + off; off += (n + 63) & ~(size_t)63; return p; };
  float* A    = alloc((size_t)B_ * TC * 192 * 64);  // x-part conv results (chunk)
  float* Y0c  = alloc((size_t)B_ * TC * 32 * 64);
  float* Y1   = alloc((size_t)B_ * T_ * 64 * 64);   // full: attention memory
  float* Z0c  = alloc((size_t)B_ * TC * 64 * 64);
  float* Z1c  = alloc((size_t)B_ * TC * 32 * 64);
  float* He0  = alloc((size_t)B_ * 32 * 64);
  float* He1  = alloc((size_t)B_ * 64 * 64);
  float* Hd0  = alloc((size_t)B_ * 64 * 64);
  float* Hd1  = alloc((size_t)B_ * 32 * 64);
  float* QBUF = alloc((size_t)B_ * 4096);
  float* QKH  = alloc((size_t)B_ * 4 * 4096);
  float* WMEM = alloc((size_t)B_ * 4 * 4096);
  float* CTXB = alloc((size_t)B_ * 4096);
  float* CTXO = alloc((size_t)B_ * 4096);
  float* wgx_e0 = alloc(64 * 1 * 3);    float* wgh_e0 = alloc(64 * 32 * 3);
  float* wcx_e0 = alloc(32 * 1 * 3);    float* wch_e0 = alloc(32 * 32 * 3);
  float* wgx_e1 = alloc(128 * 32 * 3);  float* wgh_e1 = alloc(128 * 64 * 3);
  float* wcx_e1 = alloc(64 * 32 * 3);   float* wch_e1 = alloc(64 * 64 * 3);
  float* wgx_d0 = alloc(128 * 128 * 3); float* wgh_d0 = alloc(128 * 64 * 3);
  float* wcx_d0 = alloc(64 * 128 * 3);  float* wch_d0 = alloc(64 * 64 * 3);
  float* wgx_d1 = alloc(64 * 64 * 3);   float* wgh_d1 = alloc(64 * 32 * 3);
  float* wcx_d1 = alloc(32 * 64 * 3);   float* wch_d1 = alloc(32 * 32 * 3);
  if (ws_size < off * sizeof(float)) return;  // ~320 MB needed; fail visibly

  auto pack = [&](const float* src, float* dst, int INTOT, int ic0, int icN, int OC) {
    int total = OC * icN * 3;
    pack_kernel<<<(total + 255) / 256, 256, 0, stream>>>(src, dst, INTOT, ic0, icN, total);
  };
  pack(wg_e0, wgx_e0, 33, 0, 1, 64);    pack(wg_e0, wgh_e0, 33, 1, 32, 64);
  pack(wc_e0, wcx_e0, 33, 0, 1, 32);    pack(wc_e0, wch_e0, 33, 1, 32, 32);
  pack(wg_e1, wgx_e1, 96, 0, 32, 128);  pack(wg_e1, wgh_e1, 96, 32, 64, 128);
  pack(wc_e1, wcx_e1, 96, 0, 32, 64);   pack(wc_e1, wch_e1, 96, 32, 64, 64);
  pack(wg_d0, wgx_d0, 192, 0, 128, 128);pack(wg_d0, wgh_d0, 192, 128, 64, 128);
  pack(wc_d0, wcx_d0, 192, 0, 128, 64); pack(wc_d0, wch_d0, 192, 128, 64, 64);
  pack(wg_d1, wgx_d1, 96, 0, 64, 64);   pack(wg_d1, wgh_d1, 96, 64, 32, 64);
  pack(wc_d1, wcx_d1, 96, 0, 64, 32);   pack(wc_d1, wch_d1, 96, 64, 32, 32);

  hipMemsetAsync(He0, 0, (size_t)B_ * 32 * 64 * 4, stream);
  hipMemsetAsync(He1, 0, (size_t)B_ * 64 * 64 * 4, stream);

  // -------- encoder --------
  for (int c = 0; c < NCH; ++c) {
    conv_x_kernel<1, 64, 32><<<2048, 256, 0, stream>>>(
        x + (size_t)c * TC * 64, 1, (size_t)T_ * 64, nullptr,
        wgx_e0, wcx_e0, bg_e0, bc_e0, A);
    gru_rec_kernel<32, 64><<<64, 512, 0, stream>>>(
        A, wgh_e0, wch_e0, He0, Y0c, (size_t)TC * 32 * 64, He0);
    conv_x_kernel<32, 128, 64><<<2048, 256, 0, stream>>>(
        Y0c, 32, (size_t)TC * 32 * 64, nullptr,
        wgx_e1, wcx_e1, bg_e1, bc_e1, A);
    gru_rec_kernel<64, 128><<<64, 512, 0, stream>>>(
        A, wgh_e1, wch_e1, He1, Y1 + (size_t)c * TC * 4096, (size_t)T_ * 4096, He1);
  }

  // -------- attention (query len 1, folded) --------
  const float* wq = w_qkv;
  const float* wk = w_qkv + (size_t)4096 * 4096;
  const float* wv = w_qkv + (size_t)8192 * 4096;
  // q = h1 @ wq^T + bq
  gemm64_kernel<false><<<64, 256, 0, stream>>>(wq, 4096, He1, 4096, QBUF, 4096,
                                               b_qkv, 4096, 0, 0, 0, 0, 0);
  // qk_h[e] = sum_d wk[h*1024+d, e] * q[h*1024+d]   (4 heads in one grid)
  gemm64_kernel<true><<<256, 256, 0, stream>>>(wk, 4096, QBUF, 4096, QKH, 16384,
                                               nullptr, 1024, 64,
                                               (size_t)1024 * 4096, 1024, 4096, 0);
  attn_core_kernel<<<64, 256, 0, stream>>>(QKH, QBUF, b_qkv, Y1, WMEM);
  // ctx[dg] = sum_e wv[dg,e] * wmem[head(dg),e] + bv[dg]
  gemm64_kernel<false><<<64, 256, 0, stream>>>(wv, 4096, WMEM, 16384, CTXB, 4096,
                                               b_qkv + 8192, 4096, 16,
                                               (size_t)1024 * 4096, 4096, 1024, 1024);
  // context = ctx @ w_out^T + b_out
  gemm64_kernel<false><<<64, 256, 0, stream>>>(w_out, 4096, CTXB, 4096, CTXO, 4096,
                                               b_out, 4096, 0, 0, 0, 0, 0);

  // -------- decoder --------
  for (int c = 0; c < NCH; ++c) {
    conv_x_kernel<128, 128, 64><<<2048, 256, 0, stream>>>(
        Y1 + (size_t)c * TC * 4096, 64, (size_t)T_ * 4096, CTXO,
        wgx_d0, wcx_d0, bg_d0, bc_d0, A);
    gru_rec_kernel<64, 128><<<64, 512, 0, stream>>>(
        A, wgh_d0, wch_d0, (c == 0 ? He1 : Hd0), Z0c, (size_t)TC * 4096, Hd0);
    conv_x_kernel<64, 64, 32><<<2048, 256, 0, stream>>>(
        Z0c, 64, (size_t)TC * 4096, nullptr,
        wgx_d1, wcx_d1, bg_d1, bc_d1, A);
    gru_rec_kernel<32, 64><<<64, 512, 0, stream>>>(
        A, wgh_d1, wch_d1, (c == 0 ? He0 : Hd1), Z1c, (size_t)TC * 2048, Hd1);
    final_kernel<<<512, 256, 0, stream>>>(Z1c, w_fin, b_fin, out, c * TC);
  }
}

// Round 2
// 11718.688 us; speedup vs baseline: 1.2596x; 1.2596x over previous
//
#include <hip/hip_runtime.h>
#include <cstdint>

// ---------------------------------------------------------------------------
// ConvGRU-Attention autoencoder, fp32. B=64, T=128, F=64 (1-D k=3 conv over F).
//   * conv split: x-part precomputed (parallel), h-part sequential per batch.
//   * t chunked x4 (TC=32) to bound workspace.
//   * attention: qlen==1 -> fold W_k into query, W_v past softmax (exact).
//   * R2: attention parallelized (3 kernels, 1024-block grids);
//         gru_rec weights staged in LDS (persistent for HC=32, per-step
//         restage for HC=64) to kill redundant per-thread global loads.
// ---------------------------------------------------------------------------

#define B_  64
#define T_  128
#define TC  32
#define NCH 4

__device__ __forceinline__ float wsum(float v) {
#pragma unroll
  for (int m = 32; m > 0; m >>= 1) v += __shfl_xor(v, m, 64);
  return v;
}
__device__ __forceinline__ float wmaxr(float v) {
#pragma unroll
  for (int m = 32; m > 0; m >>= 1) v = fmaxf(v, __shfl_xor(v, m, 64));
  return v;
}
__device__ __forceinline__ float sigmoidf_(float x) {
  return 1.f / (1.f + __expf(-x));
}
__device__ __forceinline__ float tanhf_(float x) {
  x = fminf(fmaxf(x, -15.f), 15.f);
  float e2 = __expf(2.f * x);
  return (e2 - 1.f) / (e2 + 1.f);
}

// --------------------------------------------------------------------------
// Repack conv weights: src [OC][INTOT][3][3] -> dst [OC][icN][3] (middle kw).
// --------------------------------------------------------------------------
__global__ __launch_bounds__(256) void pack_kernel(
    const float* __restrict__ src, float* __restrict__ dst,
    int INTOT, int ic0, int icN, int total) {
  int i = blockIdx.x * 256 + threadIdx.x;
  if (i >= total) return;
  int per_oc = icN * 3;
  int oc = i / per_oc;
  int rem = i - oc * per_oc;
  int j = rem / 3, dk = rem - j * 3;
  dst[i] = src[((size_t)(oc * INTOT + ic0 + j) * 3 + dk) * 3 + 1];
}

// --------------------------------------------------------------------------
// x-part of both convs (gates then cand) for one t-chunk. One WG per (b,tl).
// --------------------------------------------------------------------------
template <int INC, int OG, int OCC>
__global__ __launch_bounds__(256) void conv_x_kernel(
    const float* __restrict__ seq, int seqC, size_t sB,
    const float* __restrict__ ctx,
    const float* __restrict__ Wgx, const float* __restrict__ Wcx,
    const float* __restrict__ bg, const float* __restrict__ bc,
    float* __restrict__ out) {
  constexpr int OCT = OG + OCC;
  constexpr int NJ = OG / 32;
  constexpr int NJC = OCC / 32;
  const int btl = blockIdx.x;
  const int b = btl >> 5;
  const int tl = btl & 31;
  const int ocg = threadIdx.x >> 3;
  const int f0 = (threadIdx.x & 7) << 3;
  __shared__ float sin_[INC][72];

  for (int idx = threadIdx.x; idx < INC * 72; idx += 256) {
    int ic = idx / 72, ff = idx - ic * 72;
    float v = 0.f;
    if (ff >= 1 && ff <= 64) {
      int fs = ff - 1;
      v = (ic < seqC)
              ? seq[(size_t)b * sB + (size_t)tl * seqC * 64 + ic * 64 + fs]
              : ctx[((size_t)b * (INC - seqC) + (ic - seqC)) * 64 + fs];
    }
    sin_[ic][ff] = v;
  }
  __syncthreads();

  {
    float acc[NJ][8];
#pragma unroll
    for (int j = 0; j < NJ; ++j) {
      float bb = bg[ocg + 32 * j];
#pragma unroll
      for (int ff = 0; ff < 8; ++ff) acc[j][ff] = bb;
    }
    for (int ic = 0; ic < INC; ++ic) {
      float4 a4 = *(const float4*)&sin_[ic][f0];
      float4 b4 = *(const float4*)&sin_[ic][f0 + 4];
      float2 c2 = *(const float2*)&sin_[ic][f0 + 8];
      float hv[10] = {a4.x, a4.y, a4.z, a4.w, b4.x, b4.y, b4.z, b4.w, c2.x, c2.y};
#pragma unroll
      for (int j = 0; j < NJ; ++j) {
        const int oc = ocg + 32 * j;
        const float* w = Wgx + ((size_t)oc * INC + ic) * 3;
        const float w0 = w[0], w1 = w[1], w2 = w[2];
#pragma unroll
        for (int ff = 0; ff < 8; ++ff)
          acc[j][ff] = fmaf(w0, hv[ff], fmaf(w1, hv[ff + 1], fmaf(w2, hv[ff + 2], acc[j][ff])));
      }
    }
#pragma unroll
    for (int j = 0; j < NJ; ++j) {
      const int oc = ocg + 32 * j;
      float* dst = out + ((size_t)btl * OCT + oc) * 64 + f0;
      *(float4*)dst = make_float4(acc[j][0], acc[j][1], acc[j][2], acc[j][3]);
      *(float4*)(dst + 4) = make_float4(acc[j][4], acc[j][5], acc[j][6], acc[j][7]);
    }
  }
  {
    float acc[NJC][8];
#pragma unroll
    for (int j = 0; j < NJC; ++j) {
      float bb = bc[ocg + 32 * j];
#pragma unroll
      for (int ff = 0; ff < 8; ++ff) acc[j][ff] = bb;
    }
    for (int ic = 0; ic < INC; ++ic) {
      float4 a4 = *(const float4*)&sin_[ic][f0];
      float4 b4 = *(const float4*)&sin_[ic][f0 + 4];
      float2 c2 = *(const float2*)&sin_[ic][f0 + 8];
      float hv[10] = {a4.x, a4.y, a4.z, a4.w, b4.x, b4.y, b4.z, b4.w, c2.x, c2.y};
#pragma unroll
      for (int j = 0; j < NJC; ++j) {
        const int oc = ocg + 32 * j;
        const float* w = Wcx + ((size_t)oc * INC + ic) * 3;
        const float w0 = w[0], w1 = w[1], w2 = w[2];
#pragma unroll
        for (int ff = 0; ff < 8; ++ff)
          acc[j][ff] = fmaf(w0, hv[ff], fmaf(w1, hv[ff + 1], fmaf(w2, hv[ff + 2], acc[j][ff])));
      }
    }
#pragma unroll
    for (int j = 0; j < NJC; ++j) {
      const int oc = ocg + 32 * j;
      float* dst = out + ((size_t)btl * OCT + OG + oc) * 64 + f0;
      *(float4*)dst = make_float4(acc[j][0], acc[j][1], acc[j][2], acc[j][3]);
      *(float4*)(dst + 4) = make_float4(acc[j][4], acc[j][5], acc[j][6], acc[j][7]);
    }
  }
}

// --------------------------------------------------------------------------
// GRU recurrence, one WG (512 thr) per batch, weights in LDS.
// HC=32: weights persistent (54 KB LDS). HC=64: per-step restage (135 KB).
// hc rotated by lane-group (g4*8) so a wave's 4 ocg groups hit distinct banks.
// --------------------------------------------------------------------------
template <int HC, int OG>
__global__ __launch_bounds__(512) void gru_rec_kernel(
    const float* __restrict__ A,          // [b][TC][OG+HC][64]
    const float* __restrict__ Wgh,        // packed [OG][HC][3]
    const float* __restrict__ Wch,        // packed [HC][HC][3]
    const float* __restrict__ hinit,      // [b][HC][64]
    float* __restrict__ Y, size_t yB,
    float* __restrict__ hfinal) {
  constexpr int OCT = OG + HC;
  constexpr int NJ = OG / 32;
  constexpr int NJC = HC / 32;
  constexpr bool PERSIST = (HC <= 32);
  constexpr int WGH_N = OG * HC * 3;
  constexpr int WCH_N = HC * HC * 3;
  constexpr int WBUF_N = PERSIST ? (WGH_N + WCH_N) : WGH_N;
  __shared__ float smem[2 * HC * 72 + WBUF_N];
  float(*hs)[72] = (float(*)[72])smem;
  float(*rhs)[72] = (float(*)[72])(smem + HC * 72);
  float* wbuf = smem + 2 * HC * 72;

  const int b = blockIdx.x;
  const int tid = threadIdx.x;
  const int ocg = tid >> 4;
  const int g4 = ocg & 3;
  const int f0 = (tid & 15) << 2;

  for (int idx = tid; idx < HC * 72; idx += 512) {
    int c = idx / 72, ff = idx - c * 72;
    float v = 0.f;
    if (ff >= 1 && ff <= 64) v = hinit[((size_t)b * HC + c) * 64 + ff - 1];
    hs[c][ff] = v;
    rhs[c][ff] = 0.f;
  }
  if constexpr (PERSIST) {
    for (int i = tid; i < WGH_N; i += 512) wbuf[i] = Wgh[i];
    for (int i = tid; i < WCH_N; i += 512) wbuf[WGH_N + i] = Wch[i];
  }
  __syncthreads();

  for (int tl = 0; tl < TC; ++tl) {
    const float* Abt = A + ((size_t)b * TC + tl) * (OCT * 64);
    float ur[NJC][4];
    if constexpr (!PERSIST) {
      const float4* gsrc = (const float4*)Wgh;
      float4* w4 = (float4*)wbuf;
      float4 stg[WGH_N / 2048];
#pragma unroll
      for (int i = 0; i < WGH_N / 2048; ++i) stg[i] = gsrc[i * 512 + tid];
#pragma unroll
      for (int i = 0; i < WGH_N / 2048; ++i) w4[i * 512 + tid] = stg[i];
      __syncthreads();
    }
    // -------- phase A: gates --------
    {
      const float* wl = wbuf;
      float acc[NJ][4];
#pragma unroll
      for (int j = 0; j < NJ; ++j) {
        const float4 v = *(const float4*)(Abt + (ocg + 32 * j) * 64 + f0);
        acc[j][0] = v.x; acc[j][1] = v.y; acc[j][2] = v.z; acc[j][3] = v.w;
      }
#pragma unroll 4
      for (int hi = 0; hi < HC; ++hi) {
        const int hc = (hi + (g4 << 3)) & (HC - 1);
        const float4 a4 = *(const float4*)&hs[hc][f0];
        const float2 b2 = *(const float2*)&hs[hc][f0 + 4];
        const float hv[6] = {a4.x, a4.y, a4.z, a4.w, b2.x, b2.y};
#pragma unroll
        for (int j = 0; j < NJ; ++j) {
          const float* w = wl + ((ocg + 32 * j) * HC + hc) * 3;
          const float w0 = w[0], w1 = w[1], w2 = w[2];
#pragma unroll
          for (int ff = 0; ff < 4; ++ff)
            acc[j][ff] = fmaf(w0, hv[ff], fmaf(w1, hv[ff + 1], fmaf(w2, hv[ff + 2], acc[j][ff])));
        }
      }
#pragma unroll
      for (int j = 0; j < NJ; ++j) {
        const int oc = ocg + 32 * j;
#pragma unroll
        for (int ff = 0; ff < 4; ++ff) {
          float s = sigmoidf_(acc[j][ff]);
          if (j < NJC) rhs[oc][f0 + ff + 1] = s * hs[oc][f0 + ff + 1];  // r*h
          else ur[j - NJC][ff] = s;                                     // u
        }
      }
    }
    __syncthreads();
    if constexpr (!PERSIST) {
      const float4* gsrc = (const float4*)Wch;
      float4* w4 = (float4*)wbuf;
      float4 stg[WCH_N / 2048];
#pragma unroll
      for (int i = 0; i < WCH_N / 2048; ++i) stg[i] = gsrc[i * 512 + tid];
#pragma unroll
      for (int i = 0; i < WCH_N / 2048; ++i) w4[i * 512 + tid] = stg[i];
      __syncthreads();
    }
    // -------- phase B: cand + state update --------
    {
      const float* wl = PERSIST ? (wbuf + WGH_N) : wbuf;
      float acc[NJC][4];
#pragma unroll
      for (int j = 0; j < NJC; ++j) {
        const float4 v = *(const float4*)(Abt + (OG + ocg + 32 * j) * 64 + f0);
        acc[j][0] = v.x; acc[j][1] = v.y; acc[j][2] = v.z; acc[j][3] = v.w;
      }
#pragma unroll 4
      for (int hi = 0; hi < HC; ++hi) {
        const int hc = (hi + (g4 << 3)) & (HC - 1);
        const float4 a4 = *(const float4*)&rhs[hc][f0];
        const float2 b2 = *(const float2*)&rhs[hc][f0 + 4];
        const float hv[6] = {a4.x, a4.y, a4.z, a4.w, b2.x, b2.y};
#pragma unroll
        for (int j = 0; j < NJC; ++j) {
          const float* w = wl + ((ocg + 32 * j) * HC + hc) * 3;
          const float w0 = w[0], w1 = w[1], w2 = w[2];
#pragma unroll
          for (int ff = 0; ff < 4; ++ff)
            acc[j][ff] = fmaf(w0, hv[ff], fmaf(w1, hv[ff + 1], fmaf(w2, hv[ff + 2], acc[j][ff])));
        }
      }
#pragma unroll
      for (int j = 0; j < NJC; ++j) {
        const int oc = ocg + 32 * j;
        float4 yv;
#pragma unroll
        for (int ff = 0; ff < 4; ++ff) {
          float cd = tanhf_(acc[j][ff]);
          float uu = ur[j][ff];
          float hold = hs[oc][f0 + ff + 1];
          float hn = (1.f - uu) * hold + uu * cd;
          hs[oc][f0 + ff + 1] = hn;
          (&yv.x)[ff] = hn;
        }
        *(float4*)(Y + (size_t)b * yB + (size_t)tl * (HC * 64) + oc * 64 + f0) = yv;
      }
    }
    __syncthreads();
  }
  for (int idx = tid; idx < HC * 64; idx += 512) {
    int c = idx >> 6, ff = idx & 63;
    hfinal[((size_t)b * HC + c) * 64 + ff] = hs[c][ff + 1];
  }
}

// --------------------------------------------------------------------------
// Small fp32 GEMM: O[b][e] = sum_k W[e][k]*X[b][k] + bias[e], M=64.
// --------------------------------------------------------------------------
template <bool WT>
__global__ __launch_bounds__(256) void gemm64_kernel(
    const float* __restrict__ W, int wrs,
    const float* __restrict__ X, int xrs,
    float* __restrict__ O, int ors,
    const float* __restrict__ bias, int K,
    int ebh, size_t hsW, size_t hsX, size_t hsO, size_t hsB) {
  int eb = blockIdx.x;
  if (ebh > 0) {
    int h = blockIdx.x / ebh;
    eb = blockIdx.x - h * ebh;
    W += h * hsW; X += h * hsX; O += h * hsO;
    if (bias) bias += h * hsB;
  }
  const int e0 = eb * 64;
  __shared__ float Xs[64][68];
  __shared__ float Ws[64][68];
  const int tb4 = (threadIdx.x & 15) << 2;
  const int te4 = (threadIdx.x >> 4) << 2;
  float acc[4][4] = {};
  for (int k0 = 0; k0 < K; k0 += 64) {
    {
      const int row = threadIdx.x >> 2;
      const int kq = (threadIdx.x & 3) << 4;
      const float* src = X + (size_t)row * xrs + k0 + kq;
#pragma unroll
      for (int q = 0; q < 4; ++q) {
        float4 v = *(const float4*)(src + (q << 2));
        Xs[kq + (q << 2) + 0][row] = v.x;
        Xs[kq + (q << 2) + 1][row] = v.y;
        Xs[kq + (q << 2) + 2][row] = v.z;
        Xs[kq + (q << 2) + 3][row] = v.w;
      }
    }
    if (!WT) {
      const int row = threadIdx.x >> 2;
      const int kq = (threadIdx.x & 3) << 4;
      const float* src = W + (size_t)(e0 + row) * wrs + k0 + kq;
#pragma unroll
      for (int q = 0; q < 4; ++q) {
        float4 v = *(const float4*)(src + (q << 2));
        Ws[kq + (q << 2) + 0][row] = v.x;
        Ws[kq + (q << 2) + 1][row] = v.y;
        Ws[kq + (q << 2) + 2][row] = v.z;
        Ws[kq + (q << 2) + 3][row] = v.w;
      }
    } else {
      const int row = threadIdx.x >> 2;
      const int eq = (threadIdx.x & 3) << 4;
      const float* src = W + (size_t)(k0 + row) * wrs + e0 + eq;
#pragma unroll
      for (int q = 0; q < 4; ++q)
        *(float4*)&Ws[row][eq + (q << 2)] = *(const float4*)(src + (q << 2));
    }
    __syncthreads();
#pragma unroll 8
    for (int k = 0; k < 64; ++k) {
      float4 xv = *(const float4*)&Xs[k][tb4];
      float4 wv4 = *(const float4*)&Ws[k][te4];
      const float xb[4] = {xv.x, xv.y, xv.z, xv.w};
      const float we[4] = {wv4.x, wv4.y, wv4.z, wv4.w};
#pragma unroll
      for (int i = 0; i < 4; ++i)
#pragma unroll
        for (int j = 0; j < 4; ++j) acc[i][j] = fmaf(xb[i], we[j], acc[i][j]);
    }
    __syncthreads();
  }
#pragma unroll
  for (int i = 0; i < 4; ++i)
#pragma unroll
    for (int j = 0; j < 4; ++j) {
      float v = acc[i][j];
      if (bias) v += bias[e0 + te4 + j];
      O[(size_t)(tb4 + i) * ors + e0 + te4 + j] = v;
    }
}

// --------------------------------------------------------------------------
// Attention, parallel form. scores[b][h][t] = dot(qk[b,h,:], mem[b,t,:])
// grid = (B * 16 t-tiles), 4 waves = 4 heads, 8 t per block.
// --------------------------------------------------------------------------
__global__ __launch_bounds__(256) void attn_scores_kernel(
    const float* __restrict__ qkh,   // [b][4][4096]
    const float* __restrict__ mem,   // [b][128][4096]
    float* __restrict__ scores) {    // [b][4][128]
  const int b = blockIdx.x >> 4;
  const int tt = blockIdx.x & 15;
  const int h = threadIdx.x >> 6;
  const int lane = threadIdx.x & 63;
  const float4* qk4 = (const float4*)(qkh + ((size_t)b * 4 + h) * 4096);
#pragma unroll 2
  for (int ti = 0; ti < 8; ++ti) {
    const int t = tt * 8 + ti;
    const float4* m4 = (const float4*)(mem + ((size_t)b * 128 + t) * 4096);
    float s = 0.f;
    for (int e = lane; e < 1024; e += 64) {
      float4 q = qk4[e], m = m4[e];
      s = fmaf(q.x, m.x, fmaf(q.y, m.y, fmaf(q.z, m.z, fmaf(q.w, m.w, s))));
    }
    s = wsum(s);
    if (lane == 0) scores[((size_t)b * 4 + h) * 128 + t] = s;
  }
}

// softmax over t (+ q.bk bias term, /sqrt(dh)); grid = B, 4 waves = heads.
__global__ __launch_bounds__(256) void attn_softmax_kernel(
    const float* __restrict__ scores, const float* __restrict__ qbuf,
    const float* __restrict__ bqkv, float* __restrict__ attnp) {
  const int b = blockIdx.x;
  const int h = threadIdx.x >> 6;
  const int lane = threadIdx.x & 63;
  const float4* q4 = (const float4*)(qbuf + (size_t)b * 4096 + h * 1024);
  const float4* k4 = (const float4*)(bqkv + 4096 + h * 1024);
  float qb = 0.f;
#pragma unroll
  for (int d = lane; d < 256; d += 64) {
    float4 q = q4[d], k = k4[d];
    qb = fmaf(q.x, k.x, fmaf(q.y, k.y, fmaf(q.z, k.z, fmaf(q.w, k.w, qb))));
  }
  qb = wsum(qb);
  const float* sc = scores + ((size_t)b * 4 + h) * 128;
  float s0 = (sc[lane] + qb) * 0.03125f;
  float s1 = (sc[lane + 64] + qb) * 0.03125f;
  float mx = wmaxr(fmaxf(s0, s1));
  float e0v = __expf(s0 - mx), e1v = __expf(s1 - mx);
  float inv = 1.f / wsum(e0v + e1v);
  attnp[((size_t)b * 4 + h) * 128 + lane] = e0v * inv;
  attnp[((size_t)b * 4 + h) * 128 + lane + 64] = e1v * inv;
}

// wmem[b][h][e] = sum_t attn[b][h][t] * mem[b][t][e]; grid = B*16 e-blocks.
__global__ __launch_bounds__(256) void attn_wsum_kernel(
    const float* __restrict__ attnp, const float* __restrict__ mem,
    float* __restrict__ wmem) {
  const int b = blockIdx.x >> 4;
  const int eb = blockIdx.x & 15;
  const int e = eb * 256 + threadIdx.x;
  __shared__ float ap[4][128];
  for (int i = threadIdx.x; i < 512; i += 256)
    ap[i >> 7][i & 127] = attnp[(size_t)b * 512 + i];
  __syncthreads();
  float a0 = 0, a1 = 0, a2 = 0, a3 = 0;
  const float* mb = mem + (size_t)b * 128 * 4096 + e;
#pragma unroll 4
  for (int t = 0; t < 128; ++t) {
    float m = mb[(size_t)t * 4096];
    a0 = fmaf(ap[0][t], m, a0);
    a1 = fmaf(ap[1][t], m, a1);
    a2 = fmaf(ap[2][t], m, a2);
    a3 = fmaf(ap[3][t], m, a3);
  }
  wmem[((size_t)b * 4 + 0) * 4096 + e] = a0;
  wmem[((size_t)b * 4 + 1) * 4096 + e] = a1;
  wmem[((size_t)b * 4 + 2) * 4096 + e] = a2;
  wmem[((size_t)b * 4 + 3) * 4096 + e] = a3;
}

// --------------------------------------------------------------------------
// Final 1x1 conv for one t-chunk.
// --------------------------------------------------------------------------
__global__ __launch_bounds__(256) void final_kernel(
    const float* __restrict__ z1c,
    const float* __restrict__ wfin, const float* __restrict__ bfin,
    float* __restrict__ out, int tOff) {
  const int idx = blockIdx.x * 256 + threadIdx.x;
  const int f = idx & 63;
  const int tl = (idx >> 6) & 31;
  const int b = idx >> 11;
  const float* zp = z1c + ((size_t)b * TC + tl) * 2048 + f;
  float a = bfin[0];
#pragma unroll
  for (int c = 0; c < 32; ++c) a = fmaf(wfin[c], zp[c * 64], a);
  out[(size_t)b * 8192 + (size_t)(tOff + tl) * 64 + f] = a;
}

// ==========================================================================
extern "C" void kernel_launch(void* const* d_in, const int* in_sizes, int n_in,
                              void* d_out, int out_size, void* d_ws, size_t ws_size,
                              hipStream_t stream) {
  (void)in_sizes; (void)n_in; (void)out_size;
  const float* x     = (const float*)d_in[0];
  const float* wg_e0 = (const float*)d_in[1];
  const float* bg_e0 = (const float*)d_in[2];
  const float* wc_e0 = (const float*)d_in[3];
  const float* bc_e0 = (const float*)d_in[4];
  const float* wg_e1 = (const float*)d_in[5];
  const float* bg_e1 = (const float*)d_in[6];
  const float* wc_e1 = (const float*)d_in[7];
  const float* bc_e1 = (const float*)d_in[8];
  const float* wg_d0 = (const float*)d_in[9];
  const float* bg_d0 = (const float*)d_in[10];
  const float* wc_d0 = (const float*)d_in[11];
  const float* bc_d0 = (const float*)d_in[12];
  const float* wg_d1 = (const float*)d_in[13];
  const float* bg_d1 = (const float*)d_in[14];
  const float* wc_d1 = (const float*)d_in[15];
  const float* bc_d1 = (const float*)d_in[16];
  const float* w_qkv = (const float*)d_in[17];
  const float* b_qkv = (const float*)d_in[18];
  const float* w_out = (const float*)d_in[19];
  const float* b_out = (const float*)d_in[20];
  const float* w_fin = (const float*)d_in[21];
  const float* b_fin = (const float*)d_in[22];
  float* out = (float*)d_out;

  float* WS = (float*)d_ws;
  size_t off = 0;
  auto alloc = [&](size_t n) { float* p = WS + off; off += (n + 63) & ~(size_t)63; return p; };
  float* A    = alloc((size_t)B_ * TC * 192 * 64);
  float* Y0c  = alloc((size_t)B_ * TC * 32 * 64);
  float* Y1   = alloc((size_t)B_ * T_ * 64 * 64);
  float* Z0c  = alloc((size_t)B_ * TC * 64 * 64);
  float* Z1c  = alloc((size_t)B_ * TC * 32 * 64);
  float* He0  = alloc((size_t)B_ * 32 * 64);
  float* He1  = alloc((size_t)B_ * 64 * 64);
  float* Hd0  = alloc((size_t)B_ * 64 * 64);
  float* Hd1  = alloc((size_t)B_ * 32 * 64);
  float* QBUF = alloc((size_t)B_ * 4096);
  float* QKH  = alloc((size_t)B_ * 4 * 4096);
  float* WMEM = alloc((size_t)B_ * 4 * 4096);
  float* CTXB = alloc((size_t)B_ * 4096);
  float* CTXO = alloc((size_t)B_ * 4096);
  float* SCR  = alloc((size_t)B_ * 4 * 128);
  float* ATTN = alloc((size_t)B_ * 4 * 128);
  float* wgx_e0 = alloc(64 * 1 * 3);    float* wgh_e0 = alloc(64 * 32 * 3);
  float* wcx_e0 = alloc(32 * 1 * 3);    float* wch_e0 = alloc(32 * 32 * 3);
  float* wgx_e1 = alloc(128 * 32 * 3);  float* wgh_e1 = alloc(128 * 64 * 3);
  float* wcx_e1 = alloc(64 * 32 * 3);   float* wch_e1 = alloc(64 * 64 * 3);
  float* wgx_d0 = alloc(128 * 128 * 3); float* wgh_d0 = alloc(128 * 64 * 3);
  float* wcx_d0 = alloc(64 * 128 * 3);  float* wch_d0 = alloc(64 * 64 * 3);
  float* wgx_d1 = alloc(64 * 64 * 3);   float* wgh_d1 = alloc(64 * 32 * 3);
  float* wcx_d1 = alloc(32 * 64 * 3);   float* wch_d1 = alloc(32 * 32 * 3);
  if (ws_size < off * sizeof(float)) return;

  auto pack = [&](const float* src, float* dst, int INTOT, int ic0, int icN, int OC) {
    int total = OC * icN * 3;
    pack_kernel<<<(total + 255) / 256, 256, 0, stream>>>(src, dst, INTOT, ic0, icN, total);
  };
  pack(wg_e0, wgx_e0, 33, 0, 1, 64);    pack(wg_e0, wgh_e0, 33, 1, 32, 64);
  pack(wc_e0, wcx_e0, 33, 0, 1, 32);    pack(wc_e0, wch_e0, 33, 1, 32, 32);
  pack(wg_e1, wgx_e1, 96, 0, 32, 128);  pack(wg_e1, wgh_e1, 96, 32, 64, 128);
  pack(wc_e1, wcx_e1, 96, 0, 32, 64);   pack(wc_e1, wch_e1, 96, 32, 64, 64);
  pack(wg_d0, wgx_d0, 192, 0, 128, 128);pack(wg_d0, wgh_d0, 192, 128, 64, 128);
  pack(wc_d0, wcx_d0, 192, 0, 128, 64); pack(wc_d0, wch_d0, 192, 128, 64, 64);
  pack(wg_d1, wgx_d1, 96, 0, 64, 64);   pack(wg_d1, wgh_d1, 96, 64, 32, 64);
  pack(wc_d1, wcx_d1, 96, 0, 64, 32);   pack(wc_d1, wch_d1, 96, 64, 32, 32);

  hipMemsetAsync(He0, 0, (size_t)B_ * 32 * 64 * 4, stream);
  hipMemsetAsync(He1, 0, (size_t)B_ * 64 * 64 * 4, stream);

  // -------- encoder --------
  for (int c = 0; c < NCH; ++c) {
    conv_x_kernel<1, 64, 32><<<2048, 256, 0, stream>>>(
        x + (size_t)c * TC * 64, 1, (size_t)T_ * 64, nullptr,
        wgx_e0, wcx_e0, bg_e0, bc_e0, A);
    gru_rec_kernel<32, 64><<<64, 512, 0, stream>>>(
        A, wgh_e0, wch_e0, He0, Y0c, (size_t)TC * 32 * 64, He0);
    conv_x_kernel<32, 128, 64><<<2048, 256, 0, stream>>>(
        Y0c, 32, (size_t)TC * 32 * 64, nullptr,
        wgx_e1, wcx_e1, bg_e1, bc_e1, A);
    gru_rec_kernel<64, 128><<<64, 512, 0, stream>>>(
        A, wgh_e1, wch_e1, He1, Y1 + (size_t)c * TC * 4096, (size_t)T_ * 4096, He1);
  }

  // -------- attention (query len 1, folded) --------
  const float* wq = w_qkv;
  const float* wk = w_qkv + (size_t)4096 * 4096;
  const float* wv = w_qkv + (size_t)8192 * 4096;
  gemm64_kernel<false><<<64, 256, 0, stream>>>(wq, 4096, He1, 4096, QBUF, 4096,
                                               b_qkv, 4096, 0, 0, 0, 0, 0);
  gemm64_kernel<true><<<256, 256, 0, stream>>>(wk, 4096, QBUF, 4096, QKH, 16384,
                                               nullptr, 1024, 64,
                                               (size_t)1024 * 4096, 1024, 4096, 0);
  attn_scores_kernel<<<B_ * 16, 256, 0, stream>>>(QKH, Y1, SCR);
  attn_softmax_kernel<<<B_, 256, 0, stream>>>(SCR, QBUF, b_qkv, ATTN);
  attn_wsum_kernel<<<B_ * 16, 256, 0, stream>>>(ATTN, Y1, WMEM);
  gemm64_kernel<false><<<64, 256, 0, stream>>>(wv, 4096, WMEM, 16384, CTXB, 4096,
                                               b_qkv + 8192, 4096, 16,
                                               (size_t)1024 * 4096, 4096, 1024, 1024);
  gemm64_kernel<false><<<64, 256, 0, stream>>>(w_out, 4096, CTXB, 4096, CTXO, 4096,
                                               b_out, 4096, 0, 0, 0, 0, 0);

  // -------- decoder --------
  for (int c = 0; c < NCH; ++c) {
    conv_x_kernel<128, 128, 64><<<2048, 256, 0, stream>>>(
        Y1 + (size_t)c * TC * 4096, 64, (size_t)T_ * 4096, CTXO,
        wgx_d0, wcx_d0, bg_d0, bc_d0, A);
    gru_rec_kernel<64, 128><<<64, 512, 0, stream>>>(
        A, wgh_d0, wch_d0, (c == 0 ? He1 : Hd0), Z0c, (size_t)TC * 4096, Hd0);
    conv_x_kernel<64, 64, 32><<<2048, 256, 0, stream>>>(
        Z0c, 64, (size_t)TC * 4096, nullptr,
        wgx_d1, wcx_d1, bg_d1, bc_d1, A);
    gru_rec_kernel<32, 64><<<64, 512, 0, stream>>>(
        A, wgh_d1, wch_d1, (c == 0 ? He0 : Hd1), Z1c, (size_t)TC * 2048, Hd1);
    final_kernel<<<512, 256, 0, stream>>>(Z1c, w_fin, b_fin, out, c * TC);
  }
}

// Round 4
// 9829.729 us; speedup vs baseline: 1.5017x; 1.1922x over previous
//
#include <hip/hip_runtime.h>
#include <cstdint>

// ---------------------------------------------------------------------------
// ConvGRU-Attention autoencoder, fp32. B=64, T=128, F=64 (1-D k=3 conv over F).
//   * conv split: x-part precomputed (parallel), h-part sequential per batch.
//   * t chunked x4 (TC=32) to bound workspace.
//   * attention: qlen==1 -> fold W_k into query, W_v past softmax (exact).
//   * R4: gru_rec uses round-2's proven two-buffer/2-barrier LDS scheme with
//     thread-owned float4 writes + registers for h, broadcast float4 weight
//     loads from global. Ping-pong state buffers (no hinit/hfinal aliasing).
// ---------------------------------------------------------------------------

#define B_  64
#define T_  128
#define TC  32
#define NCH 4

__device__ __forceinline__ float wsum(float v) {
#pragma unroll
  for (int m = 32; m > 0; m >>= 1) v += __shfl_xor(v, m, 64);
  return v;
}
__device__ __forceinline__ float wmaxr(float v) {
#pragma unroll
  for (int m = 32; m > 0; m >>= 1) v = fmaxf(v, __shfl_xor(v, m, 64));
  return v;
}
__device__ __forceinline__ float sigmoidf_(float x) {
  return 1.f / (1.f + __expf(-x));
}
__device__ __forceinline__ float tanhf_(float x) {
  x = fminf(fmaxf(x, -15.f), 15.f);
  float e2 = __expf(2.f * x);
  return (e2 - 1.f) / (e2 + 1.f);
}

// --------------------------------------------------------------------------
// Repack conv weights: src [OC][INTOT][3][3] -> dst [OC][icN][3] (middle kw).
// --------------------------------------------------------------------------
__global__ __launch_bounds__(256) void pack_kernel(
    const float* __restrict__ src, float* __restrict__ dst,
    int INTOT, int ic0, int icN, int total) {
  int i = blockIdx.x * 256 + threadIdx.x;
  if (i >= total) return;
  int per_oc = icN * 3;
  int oc = i / per_oc;
  int rem = i - oc * per_oc;
  int j = rem / 3, dk = rem - j * 3;
  dst[i] = src[((size_t)(oc * INTOT + ic0 + j) * 3 + dk) * 3 + 1];
}

// --------------------------------------------------------------------------
// x-part of both convs (gates then cand) for one t-chunk. One WG per (b,tl).
// 256 thr: ocg = tid>>3 (0..31), f0 = (tid&7)*8. Weights via ic-tile-4
// float4 loads (16B-aligned since (oc*INC+ic0)*3 % 4 == 0 for INC mult 4).
// --------------------------------------------------------------------------
template <int INC, int OG, int OCC>
__global__ __launch_bounds__(256) void conv_x_kernel(
    const float* __restrict__ seq, int seqC, size_t sB,
    const float* __restrict__ ctx,
    const float* __restrict__ Wgx, const float* __restrict__ Wcx,
    const float* __restrict__ bg, const float* __restrict__ bc,
    float* __restrict__ out) {
  constexpr int OCT = OG + OCC;
  constexpr int NJ = OG / 32;
  constexpr int NJC = OCC / 32;
  const int btl = blockIdx.x;
  const int b = btl >> 5;
  const int tl = btl & 31;
  const int ocg = threadIdx.x >> 3;
  const int f0 = (threadIdx.x & 7) << 3;
  __shared__ float sin_[INC][72];  // halo at [0], data 1..64

  for (int idx = threadIdx.x; idx < INC * 72; idx += 256) {
    int ic = idx / 72, ff = idx - ic * 72;
    float v = 0.f;
    if (ff >= 1 && ff <= 64) {
      int fs = ff - 1;
      v = (ic < seqC)
              ? seq[(size_t)b * sB + (size_t)tl * seqC * 64 + ic * 64 + fs]
              : ctx[((size_t)b * (INC - seqC) + (ic - seqC)) * 64 + fs];
    }
    sin_[ic][ff] = v;
  }
  __syncthreads();

  if constexpr (INC >= 4) {
    // ---- gates ----
    {
      float acc[NJ][8];
#pragma unroll
      for (int j = 0; j < NJ; ++j) {
        float bb = bg[ocg + 32 * j];
#pragma unroll
        for (int ff = 0; ff < 8; ++ff) acc[j][ff] = bb;
      }
      for (int ic0 = 0; ic0 < INC; ic0 += 4) {
        float hv[4][10];
#pragma unroll
        for (int q = 0; q < 4; ++q) {
          float4 a4 = *(const float4*)&sin_[ic0 + q][f0];
          float4 b4 = *(const float4*)&sin_[ic0 + q][f0 + 4];
          float2 c2 = *(const float2*)&sin_[ic0 + q][f0 + 8];
          hv[q][0] = a4.x; hv[q][1] = a4.y; hv[q][2] = a4.z; hv[q][3] = a4.w;
          hv[q][4] = b4.x; hv[q][5] = b4.y; hv[q][6] = b4.z; hv[q][7] = b4.w;
          hv[q][8] = c2.x; hv[q][9] = c2.y;
        }
#pragma unroll
        for (int j = 0; j < NJ; ++j) {
          const int oc = ocg + 32 * j;
          const float4* w4 = (const float4*)(Wgx + ((size_t)oc * INC + ic0) * 3);
          float4 wa = w4[0], wb = w4[1], wc4 = w4[2];
          const float wt[12] = {wa.x, wa.y, wa.z, wa.w, wb.x, wb.y, wb.z, wb.w,
                                wc4.x, wc4.y, wc4.z, wc4.w};
#pragma unroll
          for (int q = 0; q < 4; ++q) {
            const float w0 = wt[3 * q], w1 = wt[3 * q + 1], w2 = wt[3 * q + 2];
#pragma unroll
            for (int ff = 0; ff < 8; ++ff)
              acc[j][ff] = fmaf(w0, hv[q][ff], fmaf(w1, hv[q][ff + 1], fmaf(w2, hv[q][ff + 2], acc[j][ff])));
          }
        }
      }
#pragma unroll
      for (int j = 0; j < NJ; ++j) {
        float* dst = out + ((size_t)btl * OCT + ocg + 32 * j) * 64 + f0;
        *(float4*)dst = make_float4(acc[j][0], acc[j][1], acc[j][2], acc[j][3]);
        *(float4*)(dst + 4) = make_float4(acc[j][4], acc[j][5], acc[j][6], acc[j][7]);
      }
    }
    // ---- cand ----
    {
      float acc[NJC][8];
#pragma unroll
      for (int j = 0; j < NJC; ++j) {
        float bb = bc[ocg + 32 * j];
#pragma unroll
        for (int ff = 0; ff < 8; ++ff) acc[j][ff] = bb;
      }
      for (int ic0 = 0; ic0 < INC; ic0 += 4) {
        float hv[4][10];
#pragma unroll
        for (int q = 0; q < 4; ++q) {
          float4 a4 = *(const float4*)&sin_[ic0 + q][f0];
          float4 b4 = *(const float4*)&sin_[ic0 + q][f0 + 4];
          float2 c2 = *(const float2*)&sin_[ic0 + q][f0 + 8];
          hv[q][0] = a4.x; hv[q][1] = a4.y; hv[q][2] = a4.z; hv[q][3] = a4.w;
          hv[q][4] = b4.x; hv[q][5] = b4.y; hv[q][6] = b4.z; hv[q][7] = b4.w;
          hv[q][8] = c2.x; hv[q][9] = c2.y;
        }
#pragma unroll
        for (int j = 0; j < NJC; ++j) {
          const int oc = ocg + 32 * j;
          const float4* w4 = (const float4*)(Wcx + ((size_t)oc * INC + ic0) * 3);
          float4 wa = w4[0], wb = w4[1], wc4 = w4[2];
          const float wt[12] = {wa.x, wa.y, wa.z, wa.w, wb.x, wb.y, wb.z, wb.w,
                                wc4.x, wc4.y, wc4.z, wc4.w};
#pragma unroll
          for (int q = 0; q < 4; ++q) {
            const float w0 = wt[3 * q], w1 = wt[3 * q + 1], w2 = wt[3 * q + 2];
#pragma unroll
            for (int ff = 0; ff < 8; ++ff)
              acc[j][ff] = fmaf(w0, hv[q][ff], fmaf(w1, hv[q][ff + 1], fmaf(w2, hv[q][ff + 2], acc[j][ff])));
          }
        }
      }
#pragma unroll
      for (int j = 0; j < NJC; ++j) {
        float* dst = out + ((size_t)btl * OCT + OG + ocg + 32 * j) * 64 + f0;
        *(float4*)dst = make_float4(acc[j][0], acc[j][1], acc[j][2], acc[j][3]);
        *(float4*)(dst + 4) = make_float4(acc[j][4], acc[j][5], acc[j][6], acc[j][7]);
      }
    }
  } else {
    // INC == 1 (encoder layer 0 x-part).
    float hv[10];
    {
      float4 a4 = *(const float4*)&sin_[0][f0];
      float4 b4 = *(const float4*)&sin_[0][f0 + 4];
      float2 c2 = *(const float2*)&sin_[0][f0 + 8];
      hv[0] = a4.x; hv[1] = a4.y; hv[2] = a4.z; hv[3] = a4.w;
      hv[4] = b4.x; hv[5] = b4.y; hv[6] = b4.z; hv[7] = b4.w;
      hv[8] = c2.x; hv[9] = c2.y;
    }
#pragma unroll
    for (int j = 0; j < NJ; ++j) {
      const int oc = ocg + 32 * j;
      const float w0 = Wgx[oc * 3], w1 = Wgx[oc * 3 + 1], w2 = Wgx[oc * 3 + 2];
      float acc[8];
#pragma unroll
      for (int ff = 0; ff < 8; ++ff)
        acc[ff] = fmaf(w0, hv[ff], fmaf(w1, hv[ff + 1], fmaf(w2, hv[ff + 2], bg[oc])));
      float* dst = out + ((size_t)btl * OCT + oc) * 64 + f0;
      *(float4*)dst = make_float4(acc[0], acc[1], acc[2], acc[3]);
      *(float4*)(dst + 4) = make_float4(acc[4], acc[5], acc[6], acc[7]);
    }
#pragma unroll
    for (int j = 0; j < NJC; ++j) {
      const int oc = ocg + 32 * j;
      const float w0 = Wcx[oc * 3], w1 = Wcx[oc * 3 + 1], w2 = Wcx[oc * 3 + 2];
      float acc[8];
#pragma unroll
      for (int ff = 0; ff < 8; ++ff)
        acc[ff] = fmaf(w0, hv[ff], fmaf(w1, hv[ff + 1], fmaf(w2, hv[ff + 2], bc[oc])));
      float* dst = out + ((size_t)btl * OCT + OG + oc) * 64 + f0;
      *(float4*)dst = make_float4(acc[0], acc[1], acc[2], acc[3]);
      *(float4*)(dst + 4) = make_float4(acc[4], acc[5], acc[6], acc[7]);
    }
  }
}

// --------------------------------------------------------------------------
// GRU recurrence v4: round-2's proven two-buffer/2-barrier scheme.
// One WG of 512 threads per batch; thread (ocg=tid>>4, f0=(tid&15)*4) owns
// NR=HC/32 rows: h[ocg+32r][f0..f0+3] in registers.
// Hs holds h, Rs holds r*h. Per step:
//   phase A: read Hs[*] -> gates; write Rs[own]=r*h; keep u in regs
//   __syncthreads();
//   phase B: read Rs[*] -> cand; h'=(1-u)h+u*tanh(c); write Hs[own], Y
//   __syncthreads();
// All LDS writes are thread-owned aligned float4; no buffer aliasing.
// Weights: global broadcast float4 (L1/L2-resident packed taps).
// --------------------------------------------------------------------------
template <int HC>
__global__ __launch_bounds__(512) void gru_rec_kernel(
    const float* __restrict__ A,          // [b][TC][3*HC][64]
    const float* __restrict__ Wgh,        // packed [2*HC][HC][3]
    const float* __restrict__ Wch,        // packed [HC][HC][3]
    const float* hinit,                   // [b][HC][64]
    float* __restrict__ Y, size_t yB,
    float* hfinal) {
  constexpr int NR = HC / 32;
  constexpr int OG = 2 * HC;
  constexpr int OCT = 3 * HC;
  const int b = blockIdx.x;
  const int tid = threadIdx.x;
  const int ocg = tid >> 4;          // 0..31
  const int f0 = (tid & 15) << 2;    // 0..60
  const int im = (f0 == 0) ? 0 : f0 - 1;
  const bool lo = (f0 == 0), hi = (f0 == 60);
  __shared__ float Hs[HC][68];
  __shared__ float Rs[HC][68];

  float hreg[NR][4];
#pragma unroll
  for (int r = 0; r < NR; ++r) {
    const int oc = ocg + 32 * r;
    const float4 v = *(const float4*)(hinit + ((size_t)b * HC + oc) * 64 + f0);
    hreg[r][0] = v.x; hreg[r][1] = v.y; hreg[r][2] = v.z; hreg[r][3] = v.w;
    *(float4*)&Hs[oc][f0] = v;
  }
  __syncthreads();

  for (int tl = 0; tl < TC; ++tl) {
    const float* Abt = A + ((size_t)b * TC + tl) * (OCT * 64);
    float accr[NR][4], accu[NR][4], accc[NR][4];
#pragma unroll
    for (int r = 0; r < NR; ++r) {
      const int oc = ocg + 32 * r;
      const float4 vr = *(const float4*)(Abt + (size_t)oc * 64 + f0);
      const float4 vu = *(const float4*)(Abt + (size_t)(HC + oc) * 64 + f0);
      const float4 vc = *(const float4*)(Abt + (size_t)(OG + oc) * 64 + f0);
      accr[r][0] = vr.x; accr[r][1] = vr.y; accr[r][2] = vr.z; accr[r][3] = vr.w;
      accu[r][0] = vu.x; accu[r][1] = vu.y; accu[r][2] = vu.z; accu[r][3] = vu.w;
      accc[r][0] = vc.x; accc[r][1] = vc.y; accc[r][2] = vc.z; accc[r][3] = vc.w;
    }
    // -------- phase A: gates (read Hs) --------
    for (int hc0 = 0; hc0 < HC; hc0 += 4) {
      float hv[4][6];
#pragma unroll
      for (int q = 0; q < 4; ++q) {
        const float4 h4 = *(const float4*)&Hs[hc0 + q][f0];
        const float hm = Hs[hc0 + q][im];
        const float hp = Hs[hc0 + q][f0 + 4];
        hv[q][0] = lo ? 0.f : hm;
        hv[q][1] = h4.x; hv[q][2] = h4.y; hv[q][3] = h4.z; hv[q][4] = h4.w;
        hv[q][5] = hi ? 0.f : hp;
      }
#pragma unroll
      for (int r = 0; r < NR; ++r) {
        {
          const float4* w4 = (const float4*)(Wgh + ((size_t)(ocg + 32 * r) * HC + hc0) * 3);
          const float4 wa = w4[0], wb = w4[1], wc4 = w4[2];
          const float wt[12] = {wa.x, wa.y, wa.z, wa.w, wb.x, wb.y, wb.z, wb.w,
                                wc4.x, wc4.y, wc4.z, wc4.w};
#pragma unroll
          for (int q = 0; q < 4; ++q) {
            const float w0 = wt[3 * q], w1 = wt[3 * q + 1], w2 = wt[3 * q + 2];
#pragma unroll
            for (int ff = 0; ff < 4; ++ff)
              accr[r][ff] = fmaf(w0, hv[q][ff], fmaf(w1, hv[q][ff + 1], fmaf(w2, hv[q][ff + 2], accr[r][ff])));
          }
        }
        {
          const float4* w4 = (const float4*)(Wgh + ((size_t)(HC + ocg + 32 * r) * HC + hc0) * 3);
          const float4 wa = w4[0], wb = w4[1], wc4 = w4[2];
          const float wt[12] = {wa.x, wa.y, wa.z, wa.w, wb.x, wb.y, wb.z, wb.w,
                                wc4.x, wc4.y, wc4.z, wc4.w};
#pragma unroll
          for (int q = 0; q < 4; ++q) {
            const float w0 = wt[3 * q], w1 = wt[3 * q + 1], w2 = wt[3 * q + 2];
#pragma unroll
            for (int ff = 0; ff < 4; ++ff)
              accu[r][ff] = fmaf(w0, hv[q][ff], fmaf(w1, hv[q][ff + 1], fmaf(w2, hv[q][ff + 2], accu[r][ff])));
          }
        }
      }
    }
    float uu[NR][4];
#pragma unroll
    for (int r = 0; r < NR; ++r) {
      float4 rh;
#pragma unroll
      for (int ff = 0; ff < 4; ++ff) {
        uu[r][ff] = sigmoidf_(accu[r][ff]);
        (&rh.x)[ff] = sigmoidf_(accr[r][ff]) * hreg[r][ff];
      }
      *(float4*)&Rs[ocg + 32 * r][f0] = rh;
    }
    __syncthreads();
    // -------- phase B: cand (read Rs) + state update --------
    for (int hc0 = 0; hc0 < HC; hc0 += 4) {
      float hv[4][6];
#pragma unroll
      for (int q = 0; q < 4; ++q) {
        const float4 h4 = *(const float4*)&Rs[hc0 + q][f0];
        const float hm = Rs[hc0 + q][im];
        const float hp = Rs[hc0 + q][f0 + 4];
        hv[q][0] = lo ? 0.f : hm;
        hv[q][1] = h4.x; hv[q][2] = h4.y; hv[q][3] = h4.z; hv[q][4] = h4.w;
        hv[q][5] = hi ? 0.f : hp;
      }
#pragma unroll
      for (int r = 0; r < NR; ++r) {
        const float4* w4 = (const float4*)(Wch + ((size_t)(ocg + 32 * r) * HC + hc0) * 3);
        const float4 wa = w4[0], wb = w4[1], wc4 = w4[2];
        const float wt[12] = {wa.x, wa.y, wa.z, wa.w, wb.x, wb.y, wb.z, wb.w,
                              wc4.x, wc4.y, wc4.z, wc4.w};
#pragma unroll
        for (int q = 0; q < 4; ++q) {
          const float w0 = wt[3 * q], w1 = wt[3 * q + 1], w2 = wt[3 * q + 2];
#pragma unroll
          for (int ff = 0; ff < 4; ++ff)
            accc[r][ff] = fmaf(w0, hv[q][ff], fmaf(w1, hv[q][ff + 1], fmaf(w2, hv[q][ff + 2], accc[r][ff])));
        }
      }
    }
#pragma unroll
    for (int r = 0; r < NR; ++r) {
      const int oc = ocg + 32 * r;
      float4 yv;
#pragma unroll
      for (int ff = 0; ff < 4; ++ff) {
        const float cd = tanhf_(accc[r][ff]);
        const float hn = fmaf(uu[r][ff], cd - hreg[r][ff], hreg[r][ff]);
        hreg[r][ff] = hn;
        (&yv.x)[ff] = hn;
      }
      *(float4*)(Y + (size_t)b * yB + (size_t)tl * (HC * 64) + (size_t)oc * 64 + f0) = yv;
      *(float4*)&Hs[oc][f0] = yv;
    }
    __syncthreads();
  }
#pragma unroll
  for (int r = 0; r < NR; ++r) {
    const int oc = ocg + 32 * r;
    *(float4*)(hfinal + ((size_t)b * HC + oc) * 64 + f0) =
        make_float4(hreg[r][0], hreg[r][1], hreg[r][2], hreg[r][3]);
  }
}

// --------------------------------------------------------------------------
// Small fp32 GEMM: O[b][e] = sum_k W[e][k]*X[b][k] + bias[e], M=64.
// --------------------------------------------------------------------------
template <bool WT>
__global__ __launch_bounds__(256) void gemm64_kernel(
    const float* __restrict__ W, int wrs,
    const float* __restrict__ X, int xrs,
    float* __restrict__ O, int ors,
    const float* __restrict__ bias, int K,
    int ebh, size_t hsW, size_t hsX, size_t hsO, size_t hsB) {
  int eb = blockIdx.x;
  if (ebh > 0) {
    int h = blockIdx.x / ebh;
    eb = blockIdx.x - h * ebh;
    W += h * hsW; X += h * hsX; O += h * hsO;
    if (bias) bias += h * hsB;
  }
  const int e0 = eb * 64;
  __shared__ float Xs[64][68];
  __shared__ float Ws[64][68];
  const int tb4 = (threadIdx.x & 15) << 2;
  const int te4 = (threadIdx.x >> 4) << 2;
  float acc[4][4] = {};
  for (int k0 = 0; k0 < K; k0 += 64) {
    {
      const int row = threadIdx.x >> 2;
      const int kq = (threadIdx.x & 3) << 4;
      const float* src = X + (size_t)row * xrs + k0 + kq;
#pragma unroll
      for (int q = 0; q < 4; ++q) {
        float4 v = *(const float4*)(src + (q << 2));
        Xs[kq + (q << 2) + 0][row] = v.x;
        Xs[kq + (q << 2) + 1][row] = v.y;
        Xs[kq + (q << 2) + 2][row] = v.z;
        Xs[kq + (q << 2) + 3][row] = v.w;
      }
    }
    if (!WT) {
      const int row = threadIdx.x >> 2;
      const int kq = (threadIdx.x & 3) << 4;
      const float* src = W + (size_t)(e0 + row) * wrs + k0 + kq;
#pragma unroll
      for (int q = 0; q < 4; ++q) {
        float4 v = *(const float4*)(src + (q << 2));
        Ws[kq + (q << 2) + 0][row] = v.x;
        Ws[kq + (q << 2) + 1][row] = v.y;
        Ws[kq + (q << 2) + 2][row] = v.z;
        Ws[kq + (q << 2) + 3][row] = v.w;
      }
    } else {
      const int row = threadIdx.x >> 2;
      const int eq = (threadIdx.x & 3) << 4;
      const float* src = W + (size_t)(k0 + row) * wrs + e0 + eq;
#pragma unroll
      for (int q = 0; q < 4; ++q)
        *(float4*)&Ws[row][eq + (q << 2)] = *(const float4*)(src + (q << 2));
    }
    __syncthreads();
#pragma unroll 8
    for (int k = 0; k < 64; ++k) {
      float4 xv = *(const float4*)&Xs[k][tb4];
      float4 wv4 = *(const float4*)&Ws[k][te4];
      const float xb[4] = {xv.x, xv.y, xv.z, xv.w};
      const float we[4] = {wv4.x, wv4.y, wv4.z, wv4.w};
#pragma unroll
      for (int i = 0; i < 4; ++i)
#pragma unroll
        for (int j = 0; j < 4; ++j) acc[i][j] = fmaf(xb[i], we[j], acc[i][j]);
    }
    __syncthreads();
  }
#pragma unroll
  for (int i = 0; i < 4; ++i)
#pragma unroll
    for (int j = 0; j < 4; ++j) {
      float v = acc[i][j];
      if (bias) v += bias[e0 + te4 + j];
      O[(size_t)(tb4 + i) * ors + e0 + te4 + j] = v;
    }
}

// --------------------------------------------------------------------------
// Attention, parallel form (qlen==1, folded).
// --------------------------------------------------------------------------
__global__ __launch_bounds__(256) void attn_scores_kernel(
    const float* __restrict__ qkh, const float* __restrict__ mem,
    float* __restrict__ scores) {
  const int b = blockIdx.x >> 4;
  const int tt = blockIdx.x & 15;
  const int h = threadIdx.x >> 6;
  const int lane = threadIdx.x & 63;
  const float4* qk4 = (const float4*)(qkh + ((size_t)b * 4 + h) * 4096);
#pragma unroll 2
  for (int ti = 0; ti < 8; ++ti) {
    const int t = tt * 8 + ti;
    const float4* m4 = (const float4*)(mem + ((size_t)b * 128 + t) * 4096);
    float s = 0.f;
    for (int e = lane; e < 1024; e += 64) {
      float4 q = qk4[e], m = m4[e];
      s = fmaf(q.x, m.x, fmaf(q.y, m.y, fmaf(q.z, m.z, fmaf(q.w, m.w, s))));
    }
    s = wsum(s);
    if (lane == 0) scores[((size_t)b * 4 + h) * 128 + t] = s;
  }
}

__global__ __launch_bounds__(256) void attn_softmax_kernel(
    const float* __restrict__ scores, const float* __restrict__ qbuf,
    const float* __restrict__ bqkv, float* __restrict__ attnp) {
  const int b = blockIdx.x;
  const int h = threadIdx.x >> 6;
  const int lane = threadIdx.x & 63;
  const float4* q4 = (const float4*)(qbuf + (size_t)b * 4096 + h * 1024);
  const float4* k4 = (const float4*)(bqkv + 4096 + h * 1024);
  float qb = 0.f;
#pragma unroll
  for (int d = lane; d < 256; d += 64) {
    float4 q = q4[d], k = k4[d];
    qb = fmaf(q.x, k.x, fmaf(q.y, k.y, fmaf(q.z, k.z, fmaf(q.w, k.w, qb))));
  }
  qb = wsum(qb);
  const float* sc = scores + ((size_t)b * 4 + h) * 128;
  float s0 = (sc[lane] + qb) * 0.03125f;
  float s1 = (sc[lane + 64] + qb) * 0.03125f;
  float mx = wmaxr(fmaxf(s0, s1));
  float e0v = __expf(s0 - mx), e1v = __expf(s1 - mx);
  float inv = 1.f / wsum(e0v + e1v);
  attnp[((size_t)b * 4 + h) * 128 + lane] = e0v * inv;
  attnp[((size_t)b * 4 + h) * 128 + lane + 64] = e1v * inv;
}

__global__ __launch_bounds__(256) void attn_wsum_kernel(
    const float* __restrict__ attnp, const float* __restrict__ mem,
    float* __restrict__ wmem) {
  const int b = blockIdx.x >> 4;
  const int eb = blockIdx.x & 15;
  const int e = eb * 256 + threadIdx.x;
  __shared__ float ap[4][128];
  for (int i = threadIdx.x; i < 512; i += 256)
    ap[i >> 7][i & 127] = attnp[(size_t)b * 512 + i];
  __syncthreads();
  float a0 = 0, a1 = 0, a2 = 0, a3 = 0;
  const float* mb = mem + (size_t)b * 128 * 4096 + e;
#pragma unroll 4
  for (int t = 0; t < 128; ++t) {
    float m = mb[(size_t)t * 4096];
    a0 = fmaf(ap[0][t], m, a0);
    a1 = fmaf(ap[1][t], m, a1);
    a2 = fmaf(ap[2][t], m, a2);
    a3 = fmaf(ap[3][t], m, a3);
  }
  wmem[((size_t)b * 4 + 0) * 4096 + e] = a0;
  wmem[((size_t)b * 4 + 1) * 4096 + e] = a1;
  wmem[((size_t)b * 4 + 2) * 4096 + e] = a2;
  wmem[((size_t)b * 4 + 3) * 4096 + e] = a3;
}

// --------------------------------------------------------------------------
// Final 1x1 conv for one t-chunk.
// --------------------------------------------------------------------------
__global__ __launch_bounds__(256) void final_kernel(
    const float* __restrict__ z1c,
    const float* __restrict__ wfin, const float* __restrict__ bfin,
    float* __restrict__ out, int tOff) {
  const int idx = blockIdx.x * 256 + threadIdx.x;
  const int f = idx & 63;
  const int tl = (idx >> 6) & 31;
  const int b = idx >> 11;
  const float* zp = z1c + ((size_t)b * TC + tl) * 2048 + f;
  float a = bfin[0];
#pragma unroll
  for (int c = 0; c < 32; ++c) a = fmaf(wfin[c], zp[c * 64], a);
  out[(size_t)b * 8192 + (size_t)(tOff + tl) * 64 + f] = a;
}

// ==========================================================================
extern "C" void kernel_launch(void* const* d_in, const int* in_sizes, int n_in,
                              void* d_out, int out_size, void* d_ws, size_t ws_size,
                              hipStream_t stream) {
  (void)in_sizes; (void)n_in; (void)out_size;
  const float* x     = (const float*)d_in[0];
  const float* wg_e0 = (const float*)d_in[1];
  const float* bg_e0 = (const float*)d_in[2];
  const float* wc_e0 = (const float*)d_in[3];
  const float* bc_e0 = (const float*)d_in[4];
  const float* wg_e1 = (const float*)d_in[5];
  const float* bg_e1 = (const float*)d_in[6];
  const float* wc_e1 = (const float*)d_in[7];
  const float* bc_e1 = (const float*)d_in[8];
  const float* wg_d0 = (const float*)d_in[9];
  const float* bg_d0 = (const float*)d_in[10];
  const float* wc_d0 = (const float*)d_in[11];
  const float* bc_d0 = (const float*)d_in[12];
  const float* wg_d1 = (const float*)d_in[13];
  const float* bg_d1 = (const float*)d_in[14];
  const float* wc_d1 = (const float*)d_in[15];
  const float* bc_d1 = (const float*)d_in[16];
  const float* w_qkv = (const float*)d_in[17];
  const float* b_qkv = (const float*)d_in[18];
  const float* w_out = (const float*)d_in[19];
  const float* b_out = (const float*)d_in[20];
  const float* w_fin = (const float*)d_in[21];
  const float* b_fin = (const float*)d_in[22];
  float* out = (float*)d_out;

  float* WS = (float*)d_ws;
  size_t off = 0;
  auto alloc = [&](size_t n) { float* p = WS + off; off += (n + 63) & ~(size_t)63; return p; };
  float* A    = alloc((size_t)B_ * TC * 192 * 64);
  float* Y0c  = alloc((size_t)B_ * TC * 32 * 64);
  float* Y1   = alloc((size_t)B_ * T_ * 64 * 64);
  float* Z0c  = alloc((size_t)B_ * TC * 64 * 64);
  float* Z1c  = alloc((size_t)B_ * TC * 32 * 64);
  float* He0p[2] = {alloc((size_t)B_ * 32 * 64), alloc((size_t)B_ * 32 * 64)};
  float* He1p[2] = {alloc((size_t)B_ * 64 * 64), alloc((size_t)B_ * 64 * 64)};
  float* Hd0p[2] = {alloc((size_t)B_ * 64 * 64), alloc((size_t)B_ * 64 * 64)};
  float* Hd1p[2] = {alloc((size_t)B_ * 32 * 64), alloc((size_t)B_ * 32 * 64)};
  float* QBUF = alloc((size_t)B_ * 4096);
  float* QKH  = alloc((size_t)B_ * 4 * 4096);
  float* WMEM = alloc((size_t)B_ * 4 * 4096);
  float* CTXB = alloc((size_t)B_ * 4096);
  float* CTXO = alloc((size_t)B_ * 4096);
  float* SCR  = alloc((size_t)B_ * 4 * 128);
  float* ATTN = alloc((size_t)B_ * 4 * 128);
  float* wgx_e0 = alloc(64 * 1 * 3);    float* wgh_e0 = alloc(64 * 32 * 3);
  float* wcx_e0 = alloc(32 * 1 * 3);    float* wch_e0 = alloc(32 * 32 * 3);
  float* wgx_e1 = alloc(128 * 32 * 3);  float* wgh_e1 = alloc(128 * 64 * 3);
  float* wcx_e1 = alloc(64 * 32 * 3);   float* wch_e1 = alloc(64 * 64 * 3);
  float* wgx_d0 = alloc(128 * 128 * 3); float* wgh_d0 = alloc(128 * 64 * 3);
  float* wcx_d0 = alloc(64 * 128 * 3);  float* wch_d0 = alloc(64 * 64 * 3);
  float* wgx_d1 = alloc(64 * 64 * 3);   float* wgh_d1 = alloc(64 * 32 * 3);
  float* wcx_d1 = alloc(32 * 64 * 3);   float* wch_d1 = alloc(32 * 32 * 3);
  if (ws_size < off * sizeof(float)) return;

  auto pack = [&](const float* src, float* dst, int INTOT, int ic0, int icN, int OC) {
    int total = OC * icN * 3;
    pack_kernel<<<(total + 255) / 256, 256, 0, stream>>>(src, dst, INTOT, ic0, icN, total);
  };
  pack(wg_e0, wgx_e0, 33, 0, 1, 64);    pack(wg_e0, wgh_e0, 33, 1, 32, 64);
  pack(wc_e0, wcx_e0, 33, 0, 1, 32);    pack(wc_e0, wch_e0, 33, 1, 32, 32);
  pack(wg_e1, wgx_e1, 96, 0, 32, 128);  pack(wg_e1, wgh_e1, 96, 32, 64, 128);
  pack(wc_e1, wcx_e1, 96, 0, 32, 64);   pack(wc_e1, wch_e1, 96, 32, 64, 64);
  pack(wg_d0, wgx_d0, 192, 0, 128, 128);pack(wg_d0, wgh_d0, 192, 128, 64, 128);
  pack(wc_d0, wcx_d0, 192, 0, 128, 64); pack(wc_d0, wch_d0, 192, 128, 64, 64);
  pack(wg_d1, wgx_d1, 96, 0, 64, 64);   pack(wg_d1, wgh_d1, 96, 64, 32, 64);
  pack(wc_d1, wcx_d1, 96, 0, 64, 32);   pack(wc_d1, wch_d1, 96, 64, 32, 32);

  hipMemsetAsync(He0p[0], 0, (size_t)B_ * 32 * 64 * 4, stream);
  hipMemsetAsync(He1p[0], 0, (size_t)B_ * 64 * 64 * 4, stream);

  // -------- encoder --------
  for (int c = 0; c < NCH; ++c) {
    conv_x_kernel<1, 64, 32><<<2048, 256, 0, stream>>>(
        x + (size_t)c * TC * 64, 1, (size_t)T_ * 64, nullptr,
        wgx_e0, wcx_e0, bg_e0, bc_e0, A);
    gru_rec_kernel<32><<<64, 512, 0, stream>>>(
        A, wgh_e0, wch_e0, He0p[c & 1], Y0c, (size_t)TC * 32 * 64, He0p[(c + 1) & 1]);
    conv_x_kernel<32, 128, 64><<<2048, 256, 0, stream>>>(
        Y0c, 32, (size_t)TC * 32 * 64, nullptr,
        wgx_e1, wcx_e1, bg_e1, bc_e1, A);
    gru_rec_kernel<64><<<64, 512, 0, stream>>>(
        A, wgh_e1, wch_e1, He1p[c & 1], Y1 + (size_t)c * TC * 4096, (size_t)T_ * 4096,
        He1p[(c + 1) & 1]);
  }
  // final states after 4 chunks are in index (4 & 1) == 0
  float* He0f = He0p[0];
  float* He1f = He1p[0];

  // -------- attention (query len 1, folded) --------
  const float* wq = w_qkv;
  const float* wk = w_qkv + (size_t)4096 * 4096;
  const float* wv = w_qkv + (size_t)8192 * 4096;
  gemm64_kernel<false><<<64, 256, 0, stream>>>(wq, 4096, He1f, 4096, QBUF, 4096,
                                               b_qkv, 4096, 0, 0, 0, 0, 0);
  gemm64_kernel<true><<<256, 256, 0, stream>>>(wk, 4096, QBUF, 4096, QKH, 16384,
                                               nullptr, 1024, 64,
                                               (size_t)1024 * 4096, 1024, 4096, 0);
  attn_scores_kernel<<<B_ * 16, 256, 0, stream>>>(QKH, Y1, SCR);
  attn_softmax_kernel<<<B_, 256, 0, stream>>>(SCR, QBUF, b_qkv, ATTN);
  attn_wsum_kernel<<<B_ * 16, 256, 0, stream>>>(ATTN, Y1, WMEM);
  gemm64_kernel<false><<<64, 256, 0, stream>>>(wv, 4096, WMEM, 16384, CTXB, 4096,
                                               b_qkv + 8192, 4096, 16,
                                               (size_t)1024 * 4096, 4096, 1024, 1024);
  gemm64_kernel<false><<<64, 256, 0, stream>>>(w_out, 4096, CTXB, 4096, CTXO, 4096,
                                               b_out, 4096, 0, 0, 0, 0, 0);

  // -------- decoder --------
  for (int c = 0; c < NCH; ++c) {
    conv_x_kernel<128, 128, 64><<<2048, 256, 0, stream>>>(
        Y1 + (size_t)c * TC * 4096, 64, (size_t)T_ * 4096, CTXO,
        wgx_d0, wcx_d0, bg_d0, bc_d0, A);
    gru_rec_kernel<64><<<64, 512, 0, stream>>>(
        A, wgh_d0, wch_d0, (c == 0 ? He1f : Hd0p[c & 1]), Z0c, (size_t)TC * 4096,
        Hd0p[(c + 1) & 1]);
    conv_x_kernel<64, 64, 32><<<2048, 256, 0, stream>>>(
        Z0c, 64, (size_t)TC * 4096, nullptr,
        wgx_d1, wcx_d1, bg_d1, bc_d1, A);
    gru_rec_kernel<32><<<64, 512, 0, stream>>>(
        A, wgh_d1, wch_d1, (c == 0 ? He0f : Hd1p[c & 1]), Z1c, (size_t)TC * 2048,
        Hd1p[(c + 1) & 1]);
    final_kernel<<<512, 256, 0, stream>>>(Z1c, w_fin, b_fin, out, c * TC);
  }
}